// Round 1
// baseline (916.836 us; speedup 1.0000x reference)
//
#include <hip/hip_runtime.h>
#include <math.h>

#define S_LEN 2048
#define BATCH 2
#define NH 8
#define DH 64
#define DM 512

typedef __attribute__((ext_vector_type(8))) short short8;
typedef __attribute__((ext_vector_type(4))) float floatx4;

__device__ __forceinline__ unsigned short f2bf(float f) {
  union { float f; unsigned u; } v; v.f = f;
  unsigned r = v.u + 0x7FFFu + ((v.u >> 16) & 1u);
  return (unsigned short)(r >> 16);
}

// ---- fp32 -> bf16 convert, 4 elements/thread ----
__global__ __launch_bounds__(256) void cvt_f32_bf16(const float* __restrict__ src,
                                                    unsigned short* __restrict__ dst, int n4) {
  int i = blockIdx.x * blockDim.x + threadIdx.x;
  if (i < n4) {
    float4 f = ((const float4*)src)[i];
    ushort4 o;
    o.x = f2bf(f.x); o.y = f2bf(f.y); o.z = f2bf(f.z); o.w = f2bf(f.w);
    ((ushort4*)dst)[i] = o;
  }
}

// ---- topo bias: bias[b,s,t] = dot(top[b,s,t,:16], top_w) + top_b ----
__global__ __launch_bounds__(256) void bias_topo(const float* __restrict__ top,
                                                 const float* __restrict__ top_w,
                                                 const float* __restrict__ top_b,
                                                 float* __restrict__ bias) {
  size_t e = (size_t)blockIdx.x * blockDim.x + threadIdx.x;
  const float4* t = (const float4*)(top + e * 16);
  const float4* w = (const float4*)top_w;
  float acc = top_b[0];
#pragma unroll
  for (int j = 0; j < 4; j++) {
    float4 tv = t[j]; float4 wv = w[j];
    acc += tv.x * wv.x + tv.y * wv.y + tv.z * wv.z + tv.w * wv.w;
  }
  bias[e] = acc;
}

// ---- bf16 GEMM: C[m,n] = sum_k A[m,k] * W[n,k] (+bias[n]) * scale ----
// A: M x 512 bf16 row-major, W: 512 x 512 bf16 row-major (N major)
// mode 0: fp32 out[m*512+n]
// mode 1: bf16 out[((b*8+h)*2048+s)*64+d]   (Q/K, bhsd)
// mode 2: bf16 out[((b*8+h)*64+d)*2048+s]   (V transposed, bhds)
__global__ __launch_bounds__(256) void gemm_bt(const unsigned short* __restrict__ A,
                                               const unsigned short* __restrict__ W,
                                               const float* __restrict__ bias,
                                               void* __restrict__ out, int mode, float scale) {
  __shared__ unsigned short As[64][72];
  __shared__ unsigned short Ws[64][72];
  const int m0 = blockIdx.x * 64, n0 = blockIdx.y * 64;
  const int tid = threadIdx.x;
  const int w = tid >> 6, l = tid & 63;
  const int lr = l & 15, lg = l >> 4;

  floatx4 acc[4];
#pragma unroll
  for (int nb = 0; nb < 4; nb++)
#pragma unroll
    for (int i = 0; i < 4; i++) acc[nb][i] = 0.f;

  const int srow = tid >> 2;          // 0..63
  const int sseg = (tid & 3) * 16;    // 0,16,32,48

  for (int k0 = 0; k0 < 512; k0 += 64) {
    const unsigned short* ap = A + (size_t)(m0 + srow) * 512 + k0 + sseg;
    const unsigned short* wp = W + (size_t)(n0 + srow) * 512 + k0 + sseg;
    *(short8*)&As[srow][sseg]     = *(const short8*)ap;
    *(short8*)&As[srow][sseg + 8] = *(const short8*)(ap + 8);
    *(short8*)&Ws[srow][sseg]     = *(const short8*)wp;
    *(short8*)&Ws[srow][sseg + 8] = *(const short8*)(wp + 8);
    __syncthreads();
#pragma unroll
    for (int kk = 0; kk < 2; kk++) {
      short8 af = *(const short8*)&As[w * 16 + lr][kk * 32 + lg * 8];
#pragma unroll
      for (int nb = 0; nb < 4; nb++) {
        short8 bf = *(const short8*)&Ws[nb * 16 + lr][kk * 32 + lg * 8];
        acc[nb] = __builtin_amdgcn_mfma_f32_16x16x32_bf16(af, bf, acc[nb], 0, 0, 0);
      }
    }
    __syncthreads();
  }

#pragma unroll
  for (int nb = 0; nb < 4; nb++) {
    const int n = n0 + nb * 16 + lr;
    const float bv = bias[n];
#pragma unroll
    for (int i = 0; i < 4; i++) {
      const int m = m0 + w * 16 + lg * 4 + i;
      float v = (acc[nb][i] + bv) * scale;
      if (mode == 0) {
        ((float*)out)[(size_t)m * 512 + n] = v;
      } else {
        const int b = m >> 11, s = m & 2047;
        const int h = n >> 6, d = n & 63;
        unsigned short* o = (unsigned short*)out;
        if (mode == 1)
          o[((size_t)(b * 8 + h) * 2048 + s) * 64 + d] = f2bf(v);
        else
          o[((size_t)(b * 8 + h) * 64 + d) * 2048 + s] = f2bf(v);
      }
    }
  }
}

// ---- flash attention with topo bias ----
// Q,K: bhsd bf16 (Q pre-scaled by 1/8); Vt: bhds bf16; bias: (B,S,S) fp32
// Out: Ob[b, s, h*64+d] bf16
__global__ __launch_bounds__(256) void attn_kernel(const unsigned short* __restrict__ Qb,
                                                   const unsigned short* __restrict__ Kb,
                                                   const unsigned short* __restrict__ Vt,
                                                   const float* __restrict__ biasb,
                                                   unsigned short* __restrict__ Ob) {
  __shared__ unsigned short P[4][16][80];  // per-wave P tile, padded
  const int q0 = blockIdx.x * 64;
  const int bh = blockIdx.y;
  const int b = bh >> 3, h = bh & 7;
  const int tid = threadIdx.x;
  const int w = tid >> 6, l = tid & 63;
  const int lr = l & 15, lg = l >> 4;

  const unsigned short* Qh = Qb + (size_t)bh * S_LEN * DH;
  const unsigned short* Kh = Kb + (size_t)bh * S_LEN * DH;
  const unsigned short* Vh = Vt + (size_t)bh * DH * S_LEN;

  const int qrow = q0 + w * 16;
  short8 qf[2];
  qf[0] = *(const short8*)(Qh + (size_t)(qrow + lr) * DH + lg * 8);
  qf[1] = *(const short8*)(Qh + (size_t)(qrow + lr) * DH + 32 + lg * 8);

  float m_i[4], l_i[4];
  floatx4 o[4];
#pragma unroll
  for (int i = 0; i < 4; i++) { m_i[i] = -1e30f; l_i[i] = 0.f; }
#pragma unroll
  for (int nd = 0; nd < 4; nd++)
#pragma unroll
    for (int i = 0; i < 4; i++) o[nd][i] = 0.f;

  const float* brow = biasb + ((size_t)b * S_LEN + qrow) * S_LEN;
  const float LOG2E = 1.44269504088896f;

  for (int k0 = 0; k0 < S_LEN; k0 += 64) {
    floatx4 sa[4];
#pragma unroll
    for (int nb = 0; nb < 4; nb++)
#pragma unroll
      for (int i = 0; i < 4; i++) sa[nb][i] = 0.f;
#pragma unroll
    for (int kk = 0; kk < 2; kk++) {
#pragma unroll
      for (int nb = 0; nb < 4; nb++) {
        short8 kf = *(const short8*)(Kh + (size_t)(k0 + nb * 16 + lr) * DH + kk * 32 + lg * 8);
        sa[nb] = __builtin_amdgcn_mfma_f32_16x16x32_bf16(qf[kk], kf, sa[nb], 0, 0, 0);
      }
    }
    // logits = sa + bias; online softmax per q-row (row = lg*4+i)
    float p[4][4];
#pragma unroll
    for (int i = 0; i < 4; i++) {
#pragma unroll
      for (int nb = 0; nb < 4; nb++) {
        float bv = brow[(size_t)(lg * 4 + i) * S_LEN + k0 + nb * 16 + lr];
        p[nb][i] = sa[nb][i] + bv;
      }
      float mx = fmaxf(fmaxf(p[0][i], p[1][i]), fmaxf(p[2][i], p[3][i]));
      mx = fmaxf(mx, __shfl_xor(mx, 1));
      mx = fmaxf(mx, __shfl_xor(mx, 2));
      mx = fmaxf(mx, __shfl_xor(mx, 4));
      mx = fmaxf(mx, __shfl_xor(mx, 8));
      float mnew = fmaxf(m_i[i], mx);
      float alpha = exp2f((m_i[i] - mnew) * LOG2E);
      float rs = 0.f;
#pragma unroll
      for (int nb = 0; nb < 4; nb++) {
        p[nb][i] = exp2f((p[nb][i] - mnew) * LOG2E);
        rs += p[nb][i];
      }
      rs += __shfl_xor(rs, 1);
      rs += __shfl_xor(rs, 2);
      rs += __shfl_xor(rs, 4);
      rs += __shfl_xor(rs, 8);
      l_i[i] = l_i[i] * alpha + rs;
      m_i[i] = mnew;
#pragma unroll
      for (int nd = 0; nd < 4; nd++) o[nd][i] *= alpha;
    }
    // P (C-layout) -> LDS -> A-layout bf16
#pragma unroll
    for (int nb = 0; nb < 4; nb++)
#pragma unroll
      for (int i = 0; i < 4; i++)
        P[w][lg * 4 + i][nb * 16 + lr] = f2bf(p[nb][i]);
    __syncthreads();
#pragma unroll
    for (int ks = 0; ks < 2; ks++) {
      short8 pf = *(const short8*)&P[w][lr][ks * 32 + lg * 8];
#pragma unroll
      for (int nd = 0; nd < 4; nd++) {
        short8 vf = *(const short8*)(Vh + (size_t)(nd * 16 + lr) * S_LEN + k0 + ks * 32 + lg * 8);
        o[nd] = __builtin_amdgcn_mfma_f32_16x16x32_bf16(pf, vf, o[nd], 0, 0, 0);
      }
    }
    __syncthreads();
  }

#pragma unroll
  for (int i = 0; i < 4; i++) {
    const float inv = 1.0f / l_i[i];
    const int s = qrow + lg * 4 + i;
#pragma unroll
    for (int nd = 0; nd < 4; nd++)
      Ob[((size_t)b * S_LEN + s) * DM + h * DH + nd * 16 + lr] = f2bf(o[nd][i] * inv);
  }
}

extern "C" void kernel_launch(void* const* d_in, const int* in_sizes, int n_in,
                              void* d_out, int out_size, void* d_ws, size_t ws_size,
                              hipStream_t stream) {
  const float* input = (const float*)d_in[0];
  const float* top   = (const float*)d_in[1];
  const float* top_w = (const float*)d_in[2];
  const float* top_b = (const float*)d_in[3];
  const float* wq = (const float*)d_in[4];
  const float* bq = (const float*)d_in[5];
  const float* wk = (const float*)d_in[6];
  const float* bk = (const float*)d_in[7];
  const float* wv = (const float*)d_in[8];
  const float* bv = (const float*)d_in[9];
  const float* wo = (const float*)d_in[10];
  const float* bo = (const float*)d_in[11];

  char* ws = (char*)d_ws;
  float* bias_ws = (float*)ws;              ws += (size_t)BATCH * S_LEN * S_LEN * 4;
  unsigned short* in_bf = (unsigned short*)ws;  ws += (size_t)BATCH * S_LEN * DM * 2;
  unsigned short* wq_bf = (unsigned short*)ws;  ws += (size_t)DM * DM * 2;
  unsigned short* wk_bf = (unsigned short*)ws;  ws += (size_t)DM * DM * 2;
  unsigned short* wv_bf = (unsigned short*)ws;  ws += (size_t)DM * DM * 2;
  unsigned short* wo_bf = (unsigned short*)ws;  ws += (size_t)DM * DM * 2;
  unsigned short* qb  = (unsigned short*)ws;    ws += (size_t)BATCH * NH * S_LEN * DH * 2;
  unsigned short* kb  = (unsigned short*)ws;    ws += (size_t)BATCH * NH * S_LEN * DH * 2;
  unsigned short* vtb = (unsigned short*)ws;    ws += (size_t)BATCH * NH * S_LEN * DH * 2;
  unsigned short* ob  = (unsigned short*)ws;    ws += (size_t)BATCH * S_LEN * DM * 2;

  const int nIn4 = BATCH * S_LEN * DM / 4;   // 524288
  const int nW4  = DM * DM / 4;              // 65536
  cvt_f32_bf16<<<nIn4 / 256, 256, 0, stream>>>(input, in_bf, nIn4);
  cvt_f32_bf16<<<nW4 / 256, 256, 0, stream>>>(wq, wq_bf, nW4);
  cvt_f32_bf16<<<nW4 / 256, 256, 0, stream>>>(wk, wk_bf, nW4);
  cvt_f32_bf16<<<nW4 / 256, 256, 0, stream>>>(wv, wv_bf, nW4);
  cvt_f32_bf16<<<nW4 / 256, 256, 0, stream>>>(wo, wo_bf, nW4);

  bias_topo<<<(BATCH * S_LEN * S_LEN) / 256, 256, 0, stream>>>(top, top_w, top_b, bias_ws);

  dim3 gg(4096 / 64, 512 / 64);
  gemm_bt<<<gg, 256, 0, stream>>>(in_bf, wq_bf, bq, qb, 1, 0.125f);
  gemm_bt<<<gg, 256, 0, stream>>>(in_bf, wk_bf, bk, kb, 1, 1.0f);
  gemm_bt<<<gg, 256, 0, stream>>>(in_bf, wv_bf, bv, vtb, 2, 1.0f);

  attn_kernel<<<dim3(S_LEN / 64, BATCH * NH), 256, 0, stream>>>(qb, kb, vtb, bias_ws, ob);

  gemm_bt<<<gg, 256, 0, stream>>>(ob, wo_bf, bo, d_out, 0, 1.0f);
}

// Round 2
// 894.567 us; speedup vs baseline: 1.0249x; 1.0249x over previous
//
#include <hip/hip_runtime.h>
#include <math.h>

#define S_LEN 2048
#define BATCH 2
#define NH 8
#define DH 64
#define DM 512

typedef __attribute__((ext_vector_type(8))) short short8;
typedef __attribute__((ext_vector_type(4))) float floatx4;

__device__ __forceinline__ unsigned short f2bf(float f) {
  union { float f; unsigned u; } v; v.f = f;
  unsigned r = v.u + 0x7FFFu + ((v.u >> 16) & 1u);
  return (unsigned short)(r >> 16);
}

// ---- fp32 -> bf16 convert, 4 elements/thread ----
__global__ __launch_bounds__(256) void cvt_f32_bf16(const float* __restrict__ src,
                                                    unsigned short* __restrict__ dst, int n4) {
  int i = blockIdx.x * blockDim.x + threadIdx.x;
  if (i < n4) {
    float4 f = ((const float4*)src)[i];
    ushort4 o;
    o.x = f2bf(f.x); o.y = f2bf(f.y); o.z = f2bf(f.z); o.w = f2bf(f.w);
    ((ushort4*)dst)[i] = o;
  }
}

// ---- 4 weight matrices in one launch (blockIdx.y selects) ----
__global__ __launch_bounds__(256) void cvt4_f32_bf16(const float* __restrict__ a, const float* __restrict__ b,
                                                     const float* __restrict__ c, const float* __restrict__ d,
                                                     unsigned short* __restrict__ oa, unsigned short* __restrict__ ob,
                                                     unsigned short* __restrict__ oc, unsigned short* __restrict__ od) {
  const float* src; unsigned short* dst;
  switch (blockIdx.y) {
    case 0: src = a; dst = oa; break;
    case 1: src = b; dst = ob; break;
    case 2: src = c; dst = oc; break;
    default: src = d; dst = od; break;
  }
  int i = blockIdx.x * blockDim.x + threadIdx.x;
  float4 f = ((const float4*)src)[i];
  ushort4 o;
  o.x = f2bf(f.x); o.y = f2bf(f.y); o.z = f2bf(f.z); o.w = f2bf(f.w);
  ((ushort4*)dst)[i] = o;
}

// ---- topo bias: bias[b,s,t] = dot(top[b,s,t,:16], top_w) + top_b ----
__global__ __launch_bounds__(256) void bias_topo(const float* __restrict__ top,
                                                 const float* __restrict__ top_w,
                                                 const float* __restrict__ top_b,
                                                 float* __restrict__ bias) {
  size_t e = (size_t)blockIdx.x * blockDim.x + threadIdx.x;
  const float4* t = (const float4*)(top + e * 16);
  const float4* w = (const float4*)top_w;
  float acc = top_b[0];
#pragma unroll
  for (int j = 0; j < 4; j++) {
    float4 tv = t[j]; float4 wv = w[j];
    acc += tv.x * wv.x + tv.y * wv.y + tv.z * wv.z + tv.w * wv.w;
  }
  bias[e] = acc;
}

// ---- bf16 GEMM: C[m,n] = (sum_k A[m,k] * W[n,k] + bias[n]) * scale ----
// mode 0: fp32 out[m*512+n]
// mode 1: bf16 out[((b*8+h)*2048+s)*64+d]   (Q/K, bhsd)
// mode 2: bf16 out[((b*8+h)*64+d)*2048+s]   (V transposed, bhds; LDS-staged store)
__global__ __launch_bounds__(256) void gemm_bt(const unsigned short* __restrict__ A,
                                               const unsigned short* __restrict__ W,
                                               const float* __restrict__ bias,
                                               void* __restrict__ out, int mode, float scale) {
  __shared__ unsigned short As[64][72];
  __shared__ unsigned short Ws[64][72];
  const int m0 = blockIdx.x * 64, n0 = blockIdx.y * 64;
  const int tid = threadIdx.x;
  const int w = tid >> 6, l = tid & 63;
  const int lr = l & 15, lg = l >> 4;

  floatx4 acc[4];
#pragma unroll
  for (int nb = 0; nb < 4; nb++)
#pragma unroll
    for (int i = 0; i < 4; i++) acc[nb][i] = 0.f;

  const int srow = tid >> 2;          // 0..63
  const int sseg = (tid & 3) * 16;    // 0,16,32,48

  for (int k0 = 0; k0 < 512; k0 += 64) {
    const unsigned short* ap = A + (size_t)(m0 + srow) * 512 + k0 + sseg;
    const unsigned short* wp = W + (size_t)(n0 + srow) * 512 + k0 + sseg;
    *(short8*)&As[srow][sseg]     = *(const short8*)ap;
    *(short8*)&As[srow][sseg + 8] = *(const short8*)(ap + 8);
    *(short8*)&Ws[srow][sseg]     = *(const short8*)wp;
    *(short8*)&Ws[srow][sseg + 8] = *(const short8*)(wp + 8);
    __syncthreads();
#pragma unroll
    for (int kk = 0; kk < 2; kk++) {
      short8 af = *(const short8*)&As[w * 16 + lr][kk * 32 + lg * 8];
#pragma unroll
      for (int nb = 0; nb < 4; nb++) {
        short8 bf = *(const short8*)&Ws[nb * 16 + lr][kk * 32 + lg * 8];
        acc[nb] = __builtin_amdgcn_mfma_f32_16x16x32_bf16(af, bf, acc[nb], 0, 0, 0);
      }
    }
    __syncthreads();
  }

  if (mode == 2) {
    // stage tile as [d_local][s_local] in As (pitch 72), then coalesced store
#pragma unroll
    for (int nb = 0; nb < 4; nb++) {
      const float bv = bias[n0 + nb * 16 + lr];
      ushort4 pk;
      pk.x = f2bf(acc[nb][0] + bv);
      pk.y = f2bf(acc[nb][1] + bv);
      pk.z = f2bf(acc[nb][2] + bv);
      pk.w = f2bf(acc[nb][3] + bv);
      *(ushort4*)&As[nb * 16 + lr][w * 16 + lg * 4] = pk;
    }
    __syncthreads();
    const int b = m0 >> 11, s_base = m0 & 2047;
    const int h = n0 >> 6;
    unsigned short* outp = (unsigned short*)out + (size_t)(b * 8 + h) * DH * S_LEN;
    const int row = tid >> 2, seg = (tid & 3) * 16;
    short8 v0 = *(const short8*)&As[row][seg];
    short8 v1 = *(const short8*)&As[row][seg + 8];
    *(short8*)(outp + (size_t)row * S_LEN + s_base + seg)     = v0;
    *(short8*)(outp + (size_t)row * S_LEN + s_base + seg + 8) = v1;
    return;
  }

#pragma unroll
  for (int nb = 0; nb < 4; nb++) {
    const int n = n0 + nb * 16 + lr;
    const float bv = bias[n];
#pragma unroll
    for (int i = 0; i < 4; i++) {
      const int m = m0 + w * 16 + lg * 4 + i;
      float v = (acc[nb][i] + bv) * scale;
      if (mode == 0) {
        ((float*)out)[(size_t)m * 512 + n] = v;
      } else {
        const int b = m >> 11, s = m & 2047;
        const int h = n >> 6, d = n & 63;
        ((unsigned short*)out)[((size_t)(b * 8 + h) * 2048 + s) * 64 + d] = f2bf(v);
      }
    }
  }
}

// ---- flash attention, transposed-S formulation ----
// Computes S^T = K·Q^T (mfma operand swap), so each lane owns one q row:
// softmax needs only 2 shuffles; P lands write-friendly; O^T = V^T·P^T.
// Q,K: bhsd bf16 (Q pre-scaled 1/8); Vt: bhds bf16; bias: (B,S,S) fp32
__global__ __launch_bounds__(256) void attn_kernel(const unsigned short* __restrict__ Qb,
                                                   const unsigned short* __restrict__ Kb,
                                                   const unsigned short* __restrict__ Vt,
                                                   const float* __restrict__ biasb,
                                                   unsigned short* __restrict__ Ob) {
  __shared__ unsigned short Ps[4][16][72];  // per-wave P[q_local][s_local], wave-private: NO barriers
  const int q0 = blockIdx.x * 64;
  const int bh = blockIdx.y;
  const int b = bh >> 3, h = bh & 7;
  const int tid = threadIdx.x;
  const int w = tid >> 6, l = tid & 63;
  const int lr = l & 15, lg = l >> 4;

  const unsigned short* Qh = Qb + (size_t)bh * S_LEN * DH;
  const unsigned short* Kh = Kb + (size_t)bh * S_LEN * DH;
  const unsigned short* Vh = Vt + (size_t)bh * DH * S_LEN;

  const int q = q0 + w * 16 + lr;
  short8 qf[2];
  qf[0] = *(const short8*)(Qh + (size_t)q * DH + lg * 8);
  qf[1] = *(const short8*)(Qh + (size_t)q * DH + 32 + lg * 8);

  float m_i = -1e30f, l_i = 0.f;
  floatx4 o[4];
#pragma unroll
  for (int nd = 0; nd < 4; nd++)
#pragma unroll
    for (int i = 0; i < 4; i++) o[nd][i] = 0.f;

  const float* brow = biasb + ((size_t)b * S_LEN + q) * S_LEN;
  const float LOG2E = 1.44269504088896f;

  for (int k0 = 0; k0 < S_LEN; k0 += 64) {
    // S^T tile: sa[nb][i] = score(q, kcol = k0 + nb*16 + lg*4 + i)
    floatx4 sa[4];
#pragma unroll
    for (int nb = 0; nb < 4; nb++)
#pragma unroll
      for (int i = 0; i < 4; i++) sa[nb][i] = 0.f;
#pragma unroll
    for (int kk = 0; kk < 2; kk++) {
#pragma unroll
      for (int nb = 0; nb < 4; nb++) {
        short8 kf = *(const short8*)(Kh + (size_t)(k0 + nb * 16 + lr) * DH + kk * 32 + lg * 8);
        sa[nb] = __builtin_amdgcn_mfma_f32_16x16x32_bf16(kf, qf[kk], sa[nb], 0, 0, 0);
      }
    }
    // add bias (float4), local 16-way max, 2-shuffle reduce over lg groups
    float p[4][4];
    float mx = -1e30f;
#pragma unroll
    for (int nb = 0; nb < 4; nb++) {
      float4 bv = *(const float4*)(brow + k0 + nb * 16 + lg * 4);
      p[nb][0] = sa[nb][0] + bv.x;
      p[nb][1] = sa[nb][1] + bv.y;
      p[nb][2] = sa[nb][2] + bv.z;
      p[nb][3] = sa[nb][3] + bv.w;
      mx = fmaxf(mx, fmaxf(fmaxf(p[nb][0], p[nb][1]), fmaxf(p[nb][2], p[nb][3])));
    }
    mx = fmaxf(mx, __shfl_xor(mx, 16));
    mx = fmaxf(mx, __shfl_xor(mx, 32));
    const float mnew = fmaxf(m_i, mx);
    const float alpha = exp2f((m_i - mnew) * LOG2E);
    float rs = 0.f;
#pragma unroll
    for (int nb = 0; nb < 4; nb++)
#pragma unroll
      for (int i = 0; i < 4; i++) {
        p[nb][i] = exp2f((p[nb][i] - mnew) * LOG2E);
        rs += p[nb][i];
      }
    rs += __shfl_xor(rs, 16);
    rs += __shfl_xor(rs, 32);
    l_i = l_i * alpha + rs;
    m_i = mnew;
#pragma unroll
    for (int nd = 0; nd < 4; nd++)
#pragma unroll
      for (int i = 0; i < 4; i++) o[nd][i] *= alpha;
    // P write: 4 consecutive s per lane -> b64 writes, wave-private LDS
#pragma unroll
    for (int nb = 0; nb < 4; nb++) {
      ushort4 pk;
      pk.x = f2bf(p[nb][0]); pk.y = f2bf(p[nb][1]);
      pk.z = f2bf(p[nb][2]); pk.w = f2bf(p[nb][3]);
      *(ushort4*)&Ps[w][lr][nb * 16 + lg * 4] = pk;
    }
    // O^T += V^T · P^T : A = V^T fragment (contiguous global), B = P fragment (b128 LDS)
#pragma unroll
    for (int kk = 0; kk < 2; kk++) {
      short8 pf = *(const short8*)&Ps[w][lr][kk * 32 + lg * 8];
#pragma unroll
      for (int nd = 0; nd < 4; nd++) {
        short8 vf = *(const short8*)(Vh + (size_t)(nd * 16 + lr) * S_LEN + k0 + kk * 32 + lg * 8);
        o[nd] = __builtin_amdgcn_mfma_f32_16x16x32_bf16(vf, pf, o[nd], 0, 0, 0);
      }
    }
  }

  const float inv = 1.0f / l_i;
#pragma unroll
  for (int nd = 0; nd < 4; nd++) {
    ushort4 st;
    st.x = f2bf(o[nd][0] * inv);
    st.y = f2bf(o[nd][1] * inv);
    st.z = f2bf(o[nd][2] * inv);
    st.w = f2bf(o[nd][3] * inv);
    *(ushort4*)(Ob + ((size_t)b * S_LEN + q) * DM + h * DH + nd * 16 + lg * 4) = st;
  }
}

extern "C" void kernel_launch(void* const* d_in, const int* in_sizes, int n_in,
                              void* d_out, int out_size, void* d_ws, size_t ws_size,
                              hipStream_t stream) {
  const float* input = (const float*)d_in[0];
  const float* top   = (const float*)d_in[1];
  const float* top_w = (const float*)d_in[2];
  const float* top_b = (const float*)d_in[3];
  const float* wq = (const float*)d_in[4];
  const float* bq = (const float*)d_in[5];
  const float* wk = (const float*)d_in[6];
  const float* bk = (const float*)d_in[7];
  const float* wv = (const float*)d_in[8];
  const float* bv = (const float*)d_in[9];
  const float* wo = (const float*)d_in[10];
  const float* bo = (const float*)d_in[11];

  char* ws = (char*)d_ws;
  float* bias_ws = (float*)ws;              ws += (size_t)BATCH * S_LEN * S_LEN * 4;
  unsigned short* in_bf = (unsigned short*)ws;  ws += (size_t)BATCH * S_LEN * DM * 2;
  unsigned short* wq_bf = (unsigned short*)ws;  ws += (size_t)DM * DM * 2;
  unsigned short* wk_bf = (unsigned short*)ws;  ws += (size_t)DM * DM * 2;
  unsigned short* wv_bf = (unsigned short*)ws;  ws += (size_t)DM * DM * 2;
  unsigned short* wo_bf = (unsigned short*)ws;  ws += (size_t)DM * DM * 2;
  unsigned short* qb  = (unsigned short*)ws;    ws += (size_t)BATCH * NH * S_LEN * DH * 2;
  unsigned short* kb  = (unsigned short*)ws;    ws += (size_t)BATCH * NH * S_LEN * DH * 2;
  unsigned short* vtb = (unsigned short*)ws;    ws += (size_t)BATCH * NH * S_LEN * DH * 2;
  unsigned short* ob  = (unsigned short*)ws;    ws += (size_t)BATCH * S_LEN * DM * 2;

  const int nIn4 = BATCH * S_LEN * DM / 4;   // 524288
  const int nW4  = DM * DM / 4;              // 65536
  cvt_f32_bf16<<<nIn4 / 256, 256, 0, stream>>>(input, in_bf, nIn4);
  cvt4_f32_bf16<<<dim3(nW4 / 256, 4), 256, 0, stream>>>(wq, wk, wv, wo, wq_bf, wk_bf, wv_bf, wo_bf);

  bias_topo<<<(BATCH * S_LEN * S_LEN) / 256, 256, 0, stream>>>(top, top_w, top_b, bias_ws);

  dim3 gg(4096 / 64, 512 / 64);
  gemm_bt<<<gg, 256, 0, stream>>>(in_bf, wq_bf, bq, qb, 1, 0.125f);
  gemm_bt<<<gg, 256, 0, stream>>>(in_bf, wk_bf, bk, kb, 1, 1.0f);
  gemm_bt<<<gg, 256, 0, stream>>>(in_bf, wv_bf, bv, vtb, 2, 1.0f);

  attn_kernel<<<dim3(S_LEN / 64, BATCH * NH), 256, 0, stream>>>(qb, kb, vtb, bias_ws, ob);

  gemm_bt<<<gg, 256, 0, stream>>>(ob, wo_bf, bo, d_out, 0, 1.0f);
}

// Round 3
// 878.433 us; speedup vs baseline: 1.0437x; 1.0184x over previous
//
#include <hip/hip_runtime.h>
#include <hip/hip_bf16.h>
#include <math.h>

#define S_LEN 2048
#define BATCH 2
#define NH 8
#define DH 64
#define DM 512
#define LOG2E 1.44269504088896f

typedef __attribute__((ext_vector_type(8))) short short8;
typedef __attribute__((ext_vector_type(4))) float floatx4;

__device__ __forceinline__ unsigned short f2bf(float f) {
  union { float f; unsigned u; } v; v.f = f;
  unsigned r = v.u + 0x7FFFu + ((v.u >> 16) & 1u);
  return (unsigned short)(r >> 16);
}

// packed f32x2 -> bf16x2 via v_cvt_pk_bf16_f32 (RNE, same as f2bf)
__device__ __forceinline__ unsigned pkbf(float a, float b) {
  __hip_bfloat162 h = __float22bfloat162_rn(make_float2(a, b));
  union { __hip_bfloat162 h; unsigned u; } v; v.h = h;
  return v.u;
}

// ---- all fp32->bf16 converts in ONE launch ----
// blocks [0,2048): input (2M elems); [2048,3072): 4 weight mats (256K each)
__global__ __launch_bounds__(256) void cvt_all(const float* __restrict__ in,
                                               const float* __restrict__ wq, const float* __restrict__ wk,
                                               const float* __restrict__ wv, const float* __restrict__ wo,
                                               unsigned short* __restrict__ in_bf,
                                               unsigned short* __restrict__ qw, unsigned short* __restrict__ kw,
                                               unsigned short* __restrict__ vw, unsigned short* __restrict__ ow) {
  int bid = blockIdx.x;
  const float* src; unsigned short* dst; int base;
  if (bid < 2048) { src = in; dst = in_bf; base = bid; }
  else {
    int wsel = (bid - 2048) >> 8;
    base = (bid - 2048) & 255;
    switch (wsel) {
      case 0: src = wq; dst = qw; break;
      case 1: src = wk; dst = kw; break;
      case 2: src = wv; dst = vw; break;
      default: src = wo; dst = ow; break;
    }
  }
  int i = base * 256 + threadIdx.x;
  float4 f = ((const float4*)src)[i];
  ((uint2*)dst)[i] = make_uint2(pkbf(f.x, f.y), pkbf(f.z, f.w));
}

// ---- topo bias in log2 domain: bias[b,s,t] = (dot(top,top_w)+top_b)*LOG2E ----
__global__ __launch_bounds__(256) void bias_topo(const float* __restrict__ top,
                                                 const float* __restrict__ top_w,
                                                 const float* __restrict__ top_b,
                                                 float* __restrict__ bias) {
  size_t e = (size_t)blockIdx.x * blockDim.x + threadIdx.x;
  const float4* t = (const float4*)(top + e * 16);
  const float4* w = (const float4*)top_w;
  float acc = top_b[0];
#pragma unroll
  for (int j = 0; j < 4; j++) {
    float4 tv = t[j]; float4 wv = w[j];
    acc += tv.x * wv.x + tv.y * wv.y + tv.z * wv.z + tv.w * wv.w;
  }
  bias[e] = acc * LOG2E;
}

// ---- bf16 GEMM: C[m,n] = (sum_k A[m,k]*W[n,k] + bias[n]) * scale ----
// qkv=1: blockIdx.z selects {Q(mode1,scale0), K(mode1), V(mode2 transposed)}
// qkv=0: single fp32 output (mode 0)
__global__ __launch_bounds__(256) void gemm_bt(const unsigned short* __restrict__ A,
                                               const unsigned short* __restrict__ W0,
                                               const unsigned short* __restrict__ W1,
                                               const unsigned short* __restrict__ W2,
                                               const float* __restrict__ b0, const float* __restrict__ b1,
                                               const float* __restrict__ b2,
                                               void* __restrict__ o0, void* __restrict__ o1, void* __restrict__ o2,
                                               int qkv, float scale0) {
  __shared__ unsigned short As[64][72];
  __shared__ unsigned short Ws[64][72];
  const int z = qkv ? blockIdx.z : 0;
  const unsigned short* W = (z == 0) ? W0 : (z == 1) ? W1 : W2;
  const float* bias = (z == 0) ? b0 : (z == 1) ? b1 : b2;
  void* out = (z == 0) ? o0 : (z == 1) ? o1 : o2;
  const int mode = qkv ? ((z == 2) ? 2 : 1) : 0;
  const float scale = (z == 0) ? scale0 : 1.0f;

  const int m0 = blockIdx.x * 64, n0 = blockIdx.y * 64;
  const int tid = threadIdx.x;
  const int w = tid >> 6, l = tid & 63;
  const int lr = l & 15, lg = l >> 4;

  floatx4 acc[4];
#pragma unroll
  for (int nb = 0; nb < 4; nb++)
#pragma unroll
    for (int i = 0; i < 4; i++) acc[nb][i] = 0.f;

  const int srow = tid >> 2;
  const int sseg = (tid & 3) * 16;

  for (int k0 = 0; k0 < 512; k0 += 64) {
    const unsigned short* ap = A + (size_t)(m0 + srow) * 512 + k0 + sseg;
    const unsigned short* wp = W + (size_t)(n0 + srow) * 512 + k0 + sseg;
    *(short8*)&As[srow][sseg]     = *(const short8*)ap;
    *(short8*)&As[srow][sseg + 8] = *(const short8*)(ap + 8);
    *(short8*)&Ws[srow][sseg]     = *(const short8*)wp;
    *(short8*)&Ws[srow][sseg + 8] = *(const short8*)(wp + 8);
    __syncthreads();
#pragma unroll
    for (int kk = 0; kk < 2; kk++) {
      short8 af = *(const short8*)&As[w * 16 + lr][kk * 32 + lg * 8];
#pragma unroll
      for (int nb = 0; nb < 4; nb++) {
        short8 bf = *(const short8*)&Ws[nb * 16 + lr][kk * 32 + lg * 8];
        acc[nb] = __builtin_amdgcn_mfma_f32_16x16x32_bf16(af, bf, acc[nb], 0, 0, 0);
      }
    }
    __syncthreads();
  }

  if (mode == 2) {
    // stage as [d_local][s_local], coalesced 16B stores
#pragma unroll
    for (int nb = 0; nb < 4; nb++) {
      const float bv = bias[n0 + nb * 16 + lr];
      unsigned lo = pkbf(acc[nb][0] + bv, acc[nb][1] + bv);
      unsigned hi = pkbf(acc[nb][2] + bv, acc[nb][3] + bv);
      *(uint2*)&As[nb * 16 + lr][w * 16 + lg * 4] = make_uint2(lo, hi);
    }
    __syncthreads();
    const int b = m0 >> 11, s_base = m0 & 2047;
    const int h = n0 >> 6;
    unsigned short* outp = (unsigned short*)out + (size_t)(b * 8 + h) * DH * S_LEN;
    const int row = tid >> 2, seg = (tid & 3) * 16;
    short8 v0 = *(const short8*)&As[row][seg];
    short8 v1 = *(const short8*)&As[row][seg + 8];
    *(short8*)(outp + (size_t)row * S_LEN + s_base + seg)     = v0;
    *(short8*)(outp + (size_t)row * S_LEN + s_base + seg + 8) = v1;
    return;
  }

#pragma unroll
  for (int nb = 0; nb < 4; nb++) {
    const int n = n0 + nb * 16 + lr;
    const float bv = bias[n];
#pragma unroll
    for (int i = 0; i < 4; i++) {
      const int m = m0 + w * 16 + lg * 4 + i;
      float v = (acc[nb][i] + bv) * scale;
      if (mode == 0) {
        ((float*)out)[(size_t)m * 512 + n] = v;
      } else {
        const int b = m >> 11, s = m & 2047;
        const int h = n >> 6, d = n & 63;
        ((unsigned short*)out)[((size_t)(b * 8 + h) * 2048 + s) * 64 + d] = f2bf(v);
      }
    }
  }
}

// ---- flash attention, transposed-S, log2-domain softmax ----
// Q pre-scaled by LOG2E/8, bias pre-scaled by LOG2E -> exp2 directly.
__global__ __launch_bounds__(256) void attn_kernel(const unsigned short* __restrict__ Qb,
                                                   const unsigned short* __restrict__ Kb,
                                                   const unsigned short* __restrict__ Vt,
                                                   const float* __restrict__ biasb,
                                                   unsigned short* __restrict__ Ob) {
  __shared__ unsigned short Ps[4][16][72];  // wave-private, no barriers
  const int q0 = blockIdx.x * 64;
  const int bh = blockIdx.y;
  const int b = bh >> 3, h = bh & 7;
  const int tid = threadIdx.x;
  const int w = tid >> 6, l = tid & 63;
  const int lr = l & 15, lg = l >> 4;

  const unsigned short* Qh = Qb + (size_t)bh * S_LEN * DH;
  const unsigned short* Kh = Kb + (size_t)bh * S_LEN * DH;
  const unsigned short* Vh = Vt + (size_t)bh * DH * S_LEN;

  const int q = q0 + w * 16 + lr;
  short8 qf[2];
  qf[0] = *(const short8*)(Qh + (size_t)q * DH + lg * 8);
  qf[1] = *(const short8*)(Qh + (size_t)q * DH + 32 + lg * 8);

  float m_i = -1e30f, l_i = 0.f;
  floatx4 o[4];
#pragma unroll
  for (int nd = 0; nd < 4; nd++)
#pragma unroll
    for (int i = 0; i < 4; i++) o[nd][i] = 0.f;

  const float* brow = biasb + ((size_t)b * S_LEN + q) * S_LEN;

  for (int k0 = 0; k0 < S_LEN; k0 += 64) {
    floatx4 sa[4];
#pragma unroll
    for (int nb = 0; nb < 4; nb++)
#pragma unroll
      for (int i = 0; i < 4; i++) sa[nb][i] = 0.f;
#pragma unroll
    for (int kk = 0; kk < 2; kk++) {
#pragma unroll
      for (int nb = 0; nb < 4; nb++) {
        short8 kf = *(const short8*)(Kh + (size_t)(k0 + nb * 16 + lr) * DH + kk * 32 + lg * 8);
        sa[nb] = __builtin_amdgcn_mfma_f32_16x16x32_bf16(kf, qf[kk], sa[nb], 0, 0, 0);
      }
    }
    float p[4][4];
    float mx = -1e30f;
#pragma unroll
    for (int nb = 0; nb < 4; nb++) {
      float4 bv = *(const float4*)(brow + k0 + nb * 16 + lg * 4);
      p[nb][0] = sa[nb][0] + bv.x;
      p[nb][1] = sa[nb][1] + bv.y;
      p[nb][2] = sa[nb][2] + bv.z;
      p[nb][3] = sa[nb][3] + bv.w;
      mx = fmaxf(mx, fmaxf(fmaxf(p[nb][0], p[nb][1]), fmaxf(p[nb][2], p[nb][3])));
    }
    mx = fmaxf(mx, __shfl_xor(mx, 16));
    mx = fmaxf(mx, __shfl_xor(mx, 32));
    const float mnew = fmaxf(m_i, mx);
    const float alpha = exp2f(m_i - mnew);
    float rs = 0.f;
#pragma unroll
    for (int nb = 0; nb < 4; nb++)
#pragma unroll
      for (int i = 0; i < 4; i++) {
        p[nb][i] = exp2f(p[nb][i] - mnew);
        rs += p[nb][i];
      }
    rs += __shfl_xor(rs, 16);
    rs += __shfl_xor(rs, 32);
    l_i = l_i * alpha + rs;
    m_i = mnew;
#pragma unroll
    for (int nd = 0; nd < 4; nd++)
#pragma unroll
      for (int i = 0; i < 4; i++) o[nd][i] *= alpha;
#pragma unroll
    for (int nb = 0; nb < 4; nb++) {
      unsigned lo = pkbf(p[nb][0], p[nb][1]);
      unsigned hi = pkbf(p[nb][2], p[nb][3]);
      *(uint2*)&Ps[w][lr][nb * 16 + lg * 4] = make_uint2(lo, hi);
    }
#pragma unroll
    for (int kk = 0; kk < 2; kk++) {
      short8 pf = *(const short8*)&Ps[w][lr][kk * 32 + lg * 8];
#pragma unroll
      for (int nd = 0; nd < 4; nd++) {
        short8 vf = *(const short8*)(Vh + (size_t)(nd * 16 + lr) * S_LEN + k0 + kk * 32 + lg * 8);
        o[nd] = __builtin_amdgcn_mfma_f32_16x16x32_bf16(vf, pf, o[nd], 0, 0, 0);
      }
    }
  }

  const float inv = 1.0f / l_i;
#pragma unroll
  for (int nd = 0; nd < 4; nd++) {
    unsigned lo = pkbf(o[nd][0] * inv, o[nd][1] * inv);
    unsigned hi = pkbf(o[nd][2] * inv, o[nd][3] * inv);
    *(uint2*)(Ob + ((size_t)b * S_LEN + q) * DM + h * DH + nd * 16 + lg * 4) = make_uint2(lo, hi);
  }
}

extern "C" void kernel_launch(void* const* d_in, const int* in_sizes, int n_in,
                              void* d_out, int out_size, void* d_ws, size_t ws_size,
                              hipStream_t stream) {
  const float* input = (const float*)d_in[0];
  const float* top   = (const float*)d_in[1];
  const float* top_w = (const float*)d_in[2];
  const float* top_b = (const float*)d_in[3];
  const float* wq = (const float*)d_in[4];
  const float* bq = (const float*)d_in[5];
  const float* wk = (const float*)d_in[6];
  const float* bk = (const float*)d_in[7];
  const float* wv = (const float*)d_in[8];
  const float* bv = (const float*)d_in[9];
  const float* wo = (const float*)d_in[10];
  const float* bo = (const float*)d_in[11];

  char* ws = (char*)d_ws;
  float* bias_ws = (float*)ws;              ws += (size_t)BATCH * S_LEN * S_LEN * 4;
  unsigned short* in_bf = (unsigned short*)ws;  ws += (size_t)BATCH * S_LEN * DM * 2;
  unsigned short* wq_bf = (unsigned short*)ws;  ws += (size_t)DM * DM * 2;
  unsigned short* wk_bf = (unsigned short*)ws;  ws += (size_t)DM * DM * 2;
  unsigned short* wv_bf = (unsigned short*)ws;  ws += (size_t)DM * DM * 2;
  unsigned short* wo_bf = (unsigned short*)ws;  ws += (size_t)DM * DM * 2;
  unsigned short* qb  = (unsigned short*)ws;    ws += (size_t)BATCH * NH * S_LEN * DH * 2;
  unsigned short* kb  = (unsigned short*)ws;    ws += (size_t)BATCH * NH * S_LEN * DH * 2;
  unsigned short* vtb = (unsigned short*)ws;    ws += (size_t)BATCH * NH * S_LEN * DH * 2;
  unsigned short* ob  = (unsigned short*)ws;    ws += (size_t)BATCH * S_LEN * DM * 2;

  cvt_all<<<3072, 256, 0, stream>>>(input, wq, wk, wv, wo, in_bf, wq_bf, wk_bf, wv_bf, wo_bf);

  bias_topo<<<(BATCH * S_LEN * S_LEN) / 256, 256, 0, stream>>>(top, top_w, top_b, bias_ws);

  gemm_bt<<<dim3(4096 / 64, 512 / 64, 3), 256, 0, stream>>>(
      in_bf, wq_bf, wk_bf, wv_bf, bq, bk, bv, qb, kb, vtb, 1, 0.125f * LOG2E);

  attn_kernel<<<dim3(S_LEN / 64, BATCH * NH), 256, 0, stream>>>(qb, kb, vtb, bias_ws, ob);

  gemm_bt<<<dim3(4096 / 64, 512 / 64, 1), 256, 0, stream>>>(
      ob, wo_bf, nullptr, nullptr, bo, nullptr, nullptr, d_out, nullptr, nullptr, 0, 1.0f);
}